// Round 8
// baseline (405.462 us; speedup 1.0000x reference)
//
#include <hip/hip_runtime.h>
#include <hip/hip_bf16.h>

// NA Spatial MSA, fused:  out = attn @ (xw @ (Wv@Wo)) + bo
// R8: BARRIER-FREE. No LDS, no __syncthreads. Each wave owns a 32-channel
// slice of one window and runs the full pipeline privately:
//   GEMM1 A: gathered from global x (lane=tok-row, 32B/lane/ks, imm offsets;
//            8 waves/window re-read via L1/L2)
//   GEMM1 B: WT from L2 (128KB, chip-resident)
//   z -> GEMM2 B: in-register pack + shfl_xor(32)   (proven R3/R5/R7)
//   GEMM2 A: gathered from global attn
// Waves desync freely -> continuous mixed HBM read+write traffic (R2-R7 all
// capped at ~2.5 TB/s from barrier-lockstep phase serialization).

typedef __bf16 bf16x8 __attribute__((ext_vector_type(8)));
typedef float  f32x16 __attribute__((ext_vector_type(16)));
typedef float  f32x4  __attribute__((ext_vector_type(4)));
typedef unsigned int uint;
typedef uint   uint4v __attribute__((ext_vector_type(4)));

#define MFMA32(a, b, c) __builtin_amdgcn_mfma_f32_32x32x16_bf16(a, b, c, 0, 0, 0)

// ---------------- Stage 0: WT = (Wv @ Wo)^T in bf16 ----------------
__global__ void wfuse_kernel(const float* __restrict__ Wv,
                             const float* __restrict__ Wo,
                             __bf16* __restrict__ WT) {
  const int n = blockIdx.x;
  const int k = threadIdx.x;
  const float* wvrow = Wv + k * 256;
  float acc = 0.f;
#pragma unroll 4
  for (int j = 0; j < 256; j += 4) {
    f32x4 wv = *(const f32x4*)(wvrow + j);
    acc += wv.x * Wo[(j + 0) * 256 + n];
    acc += wv.y * Wo[(j + 1) * 256 + n];
    acc += wv.z * Wo[(j + 2) * 256 + n];
    acc += wv.w * Wo[(j + 3) * 256 + n];
  }
  WT[n * 256 + k] = (__bf16)acc;
}

static __device__ __forceinline__ uint pkbf(float lo, float hi) {
  return (uint)__builtin_bit_cast(unsigned short, (__bf16)lo) |
         ((uint)__builtin_bit_cast(unsigned short, (__bf16)hi) << 16);
}

static __device__ __forceinline__ bf16x8 cvt8(f32x4 u, f32x4 v) {
  bf16x8 r;
  r[0] = (__bf16)u.x; r[1] = (__bf16)u.y; r[2] = (__bf16)u.z; r[3] = (__bf16)u.w;
  r[4] = (__bf16)v.x; r[5] = (__bf16)v.y; r[6] = (__bf16)v.z; r[7] = (__bf16)v.w;
  return r;
}

// GEMM2 B-frags from GEMM1 acc via pack + shfl_xor(32). (verified R3/R5/R7)
static __device__ __forceinline__ void build_bfrags(const f32x16 acc, int lh,
                                                    bf16x8* bf) {
  uint wd0 = pkbf(acc[0],  acc[1]);
  uint wd1 = pkbf(acc[2],  acc[3]);
  uint wd2 = pkbf(acc[4],  acc[5]);
  uint wd3 = pkbf(acc[6],  acc[7]);
  uint wd4 = pkbf(acc[8],  acc[9]);
  uint wd5 = pkbf(acc[10], acc[11]);
  uint wd6 = pkbf(acc[12], acc[13]);
  uint wd7 = pkbf(acc[14], acc[15]);
  {
    uint o0 = (uint)__shfl_xor((int)wd2, 32);
    uint o1 = (uint)__shfl_xor((int)wd3, 32);
    uint o2 = (uint)__shfl_xor((int)wd0, 32);
    uint o3 = (uint)__shfl_xor((int)wd1, 32);
    uint4v uv = { lh ? o0 : wd0, lh ? o1 : wd1,
                  lh ? wd2 : o2, lh ? wd3 : o3 };
    bf[0] = __builtin_bit_cast(bf16x8, uv);
  }
  {
    uint o0 = (uint)__shfl_xor((int)wd6, 32);
    uint o1 = (uint)__shfl_xor((int)wd7, 32);
    uint o2 = (uint)__shfl_xor((int)wd4, 32);
    uint o3 = (uint)__shfl_xor((int)wd5, 32);
    uint4v uv = { lh ? o0 : wd4, lh ? o1 : wd5,
                  lh ? wd6 : o2, lh ? wd7 : o3 };
    bf[1] = __builtin_bit_cast(bf16x8, uv);
  }
}

static __device__ __forceinline__ long wbase(int w) {
  int wi = w & 31;
  int hi = (w >> 5) & 31;
  int b  = w >> 10;
  return (((long)(b * 256 + hi * 8)) * 256 + wi * 8) * 256;
}

// ---------------- Main kernel: no LDS, no barriers ----------------
__global__ __launch_bounds__(512)
void na_msa_kernel(const float* __restrict__ x,
                   const float* __restrict__ attn,
                   const __bf16* __restrict__ WT,
                   const float* __restrict__ bo,
                   float* __restrict__ out) {
  const int t    = threadIdx.x;
  const int lane = t & 63;
  const int wvi  = t >> 6;              // wave 0..7, owns ch [32wvi, 32wvi+32)
  const int ln31 = lane & 31;
  const int lh   = lane >> 5;

  const int w = blockIdx.x;             // window id (8 waves share it via L1/L2)
  const long base = wbase(w);
  const float* xp = x + base;
  const float* ap = attn + (long)w * 4096;

  const __bf16* wtp = WT + (wvi * 32 + ln31) * 256 + 8 * lh;
  const float bv = bo[wvi * 32 + ln31];

  // per-lane gather bases: tokA = ln31, tokB = 32+ln31
  const int tokA = ln31, tokB = 32 + ln31;
  const float* xA = xp + (tokA >> 3) * 65536 + (tokA & 7) * 256 + 8 * lh;
  const float* xB = xp + (tokB >> 3) * 65536 + (tokB & 7) * 256 + 8 * lh;

  // ---- GEMM1: z[tok][ch] = x @ W, K=256. A gathered from global. ----
  // lane reads 32B (x[tok][k..k+8)) per ks at imm offset ks*64B; the lh pair
  // covers a full 64B sector; the ks sweep consumes each line fully.
  f32x16 acc0 = {}, acc1 = {};
#pragma unroll
  for (int ks = 0; ks < 16; ++ks) {
    f32x4 u0 = *(const f32x4*)(xA + ks * 16);
    f32x4 v0 = *(const f32x4*)(xA + ks * 16 + 4);
    f32x4 u1 = *(const f32x4*)(xB + ks * 16);
    f32x4 v1 = *(const f32x4*)(xB + ks * 16 + 4);
    bf16x8 b0 = *(const bf16x8*)(wtp + ks * 16);   // L2/L1-resident
    acc0 = MFMA32(cvt8(u0, v0), b0, acc0);
    acc1 = MFMA32(cvt8(u1, v1), b0, acc1);
  }

  // ---- GEMM2 B-frags in-register ----
  bf16x8 bfr[4];
  build_bfrags(acc0, lh, &bfr[0]);   // ks 0,1 (toks 0..31)
  build_bfrags(acc1, lh, &bfr[2]);   // ks 2,3 (toks 32..63)

  // ---- GEMM2: out[tok][ch] = attn @ z, K=64. A gathered from global. ----
  const float* aA = ap + tokA * 64 + 8 * lh;
  const float* aB = ap + tokB * 64 + 8 * lh;
  f32x16 o0 = {}, o1 = {};
#pragma unroll
  for (int ks = 0; ks < 4; ++ks) {
    f32x4 u0 = *(const f32x4*)(aA + ks * 16);
    f32x4 v0 = *(const f32x4*)(aA + ks * 16 + 4);
    f32x4 u1 = *(const f32x4*)(aB + ks * 16);
    f32x4 v1 = *(const f32x4*)(aB + ks * 16 + 4);
    o0 = MFMA32(cvt8(u0, v0), bfr[ks], o0);
    o1 = MFMA32(cvt8(u1, v1), bfr[ks], o1);
  }

  // ---- epilogue: + bo, scatter to (b,h,w,c). lanes 0-31 = consecutive ch ----
  float* op = out + base;
  const int ch = wvi * 32 + ln31;
#pragma unroll
  for (int r = 0; r < 16; ++r) {
    int tok = (r & 3) + 8 * (r >> 2) + 4 * lh;              // o0: toks 0..31
    op[(tok >> 3) * 65536 + (tok & 7) * 256 + ch] = o0[r] + bv;
  }
#pragma unroll
  for (int r = 0; r < 16; ++r) {
    int tok = 32 + (r & 3) + 8 * (r >> 2) + 4 * lh;         // o1: toks 32..63
    op[(tok >> 3) * 65536 + (tok & 7) * 256 + ch] = o1[r] + bv;
  }
}

extern "C" void kernel_launch(void* const* d_in, const int* in_sizes, int n_in,
                              void* d_out, int out_size, void* d_ws, size_t ws_size,
                              hipStream_t stream) {
  const float* x    = (const float*)d_in[0];
  const float* attn = (const float*)d_in[1];
  const float* Wv   = (const float*)d_in[2];
  const float* Wo   = (const float*)d_in[3];
  const float* bo   = (const float*)d_in[4];
  float* out = (float*)d_out;
  __bf16* WT = (__bf16*)d_ws;   // 256*256*2 = 128 KB scratch

  wfuse_kernel<<<256, 256, 0, stream>>>(Wv, Wo, WT);
  na_msa_kernel<<<4096, 512, 0, stream>>>(x, attn, WT, bo, out);
}

// Round 9
// 174.315 us; speedup vs baseline: 2.3260x; 2.3260x over previous
//
#include <hip/hip_runtime.h>
#include <hip/hip_bf16.h>

// NA Spatial MSA, fused:  out = attn @ (xw @ (Wv@Wo)) + bo
// R9 = R7 with ONE change: loop-end s_waitcnt vmcnt(0) -> vmcnt(32).
// The 32 scatter stores (newest VMEM ops) stay in flight across the barrier
// and drain under the next window's compute; only the 8 next-window DMAs and
// the attn loads (all a full compute-phase old) must complete. T4: never
// drain vmcnt to 0 in the main loop. R2/R5/R7 all paid a full store-ack
// round trip per window inside the vmcnt(0)+barrier -> ~2.5 TB/s cap.

typedef __bf16 bf16x8 __attribute__((ext_vector_type(8)));
typedef __bf16 bf16x4 __attribute__((ext_vector_type(4)));
typedef float  f32x16 __attribute__((ext_vector_type(16)));
typedef float  f32x4  __attribute__((ext_vector_type(4)));
typedef unsigned int uint;
typedef uint   uint4v __attribute__((ext_vector_type(4)));

#define MFMA32(a, b, c) __builtin_amdgcn_mfma_f32_32x32x16_bf16(a, b, c, 0, 0, 0)

// ---------------- Stage 0: WT = (Wv @ Wo)^T in bf16 ----------------
__global__ void wfuse_kernel(const float* __restrict__ Wv,
                             const float* __restrict__ Wo,
                             __bf16* __restrict__ WT) {
  const int n = blockIdx.x;
  const int k = threadIdx.x;
  const float* wvrow = Wv + k * 256;
  float acc = 0.f;
#pragma unroll 4
  for (int j = 0; j < 256; j += 4) {
    f32x4 wv = *(const f32x4*)(wvrow + j);
    acc += wv.x * Wo[(j + 0) * 256 + n];
    acc += wv.y * Wo[(j + 1) * 256 + n];
    acc += wv.z * Wo[(j + 2) * 256 + n];
    acc += wv.w * Wo[(j + 3) * 256 + n];
  }
  WT[n * 256 + k] = (__bf16)acc;
}

static __device__ __forceinline__ uint pkbf(float lo, float hi) {
  return (uint)__builtin_bit_cast(unsigned short, (__bf16)lo) |
         ((uint)__builtin_bit_cast(unsigned short, (__bf16)hi) << 16);
}

// GEMM2 B-frags from GEMM1 acc via pack + shfl_xor(32). (verified R3/R5/R7)
static __device__ __forceinline__ void build_bfrags(const f32x16 acc, int lh,
                                                    bf16x8* bf) {
  uint wd0 = pkbf(acc[0],  acc[1]);
  uint wd1 = pkbf(acc[2],  acc[3]);
  uint wd2 = pkbf(acc[4],  acc[5]);
  uint wd3 = pkbf(acc[6],  acc[7]);
  uint wd4 = pkbf(acc[8],  acc[9]);
  uint wd5 = pkbf(acc[10], acc[11]);
  uint wd6 = pkbf(acc[12], acc[13]);
  uint wd7 = pkbf(acc[14], acc[15]);
  {
    uint o0 = (uint)__shfl_xor((int)wd2, 32);
    uint o1 = (uint)__shfl_xor((int)wd3, 32);
    uint o2 = (uint)__shfl_xor((int)wd0, 32);
    uint o3 = (uint)__shfl_xor((int)wd1, 32);
    uint4v uv = { lh ? o0 : wd0, lh ? o1 : wd1,
                  lh ? wd2 : o2, lh ? wd3 : o3 };
    bf[0] = __builtin_bit_cast(bf16x8, uv);
  }
  {
    uint o0 = (uint)__shfl_xor((int)wd6, 32);
    uint o1 = (uint)__shfl_xor((int)wd7, 32);
    uint o2 = (uint)__shfl_xor((int)wd4, 32);
    uint o3 = (uint)__shfl_xor((int)wd5, 32);
    uint4v uv = { lh ? o0 : wd4, lh ? o1 : wd5,
                  lh ? wd6 : o2, lh ? wd7 : o3 };
    bf[1] = __builtin_bit_cast(bf16x8, uv);
  }
}

static __device__ __forceinline__ long wbase(int w) {
  int wi = w & 31;
  int hi = (w >> 5) & 31;
  int b  = w >> 10;
  return (((long)(b * 256 + hi * 8)) * 256 + wi * 8) * 256;
}

// async 16B/lane global->LDS DMA (LDS dest = wave-uniform base + lane*16)
static __device__ __forceinline__ void dma16(const float* gp, char* lp) {
  __builtin_amdgcn_global_load_lds(
      (const __attribute__((address_space(1))) uint*)gp,
      (__attribute__((address_space(3))) uint*)lp, 16, 0, 0);
}

// read bf16x8 A-frag from f32 x-strip (swizzle: granule p = g ^ (tok&31))
static __device__ __forceinline__ bf16x8 ldax(const char* xs, int tok, int g) {
  const int sw = tok & 31;
  f32x4 u = *(const f32x4*)(xs + tok * 1024 + ((g ^ sw) << 4));
  f32x4 v = *(const f32x4*)(xs + tok * 1024 + (((g + 1) ^ sw) << 4));
  bf16x8 r;
  r[0] = (__bf16)u.x; r[1] = (__bf16)u.y; r[2] = (__bf16)u.z; r[3] = (__bf16)u.w;
  r[4] = (__bf16)v.x; r[5] = (__bf16)v.y; r[6] = (__bf16)v.z; r[7] = (__bf16)v.w;
  return r;
}

// ---------------- Main kernel ----------------
// LDS 144KB: x-f32 strips at 0 / 65536; attn-bf16 strips at 131072 / 139264.
__global__ __launch_bounds__(512)
void na_msa_kernel(const float* __restrict__ x,
                   const float* __restrict__ attn,
                   const __bf16* __restrict__ WT,
                   const float* __restrict__ bo,
                   float* __restrict__ out) {
  __shared__ char lds[147456];

  const int t    = threadIdx.x;
  const int lane = t & 63;
  const int wvi  = t >> 6;              // wave 0..7, owns ch [32wvi, 32wvi+32)
  const int ln31 = lane & 31;
  const int lh   = lane >> 5;

  const __bf16* wtp = WT + (wvi * 32 + ln31) * 256 + 8 * lh;
  const float bv = bo[wvi * 32 + ln31];

  // attn VGPR-staging geometry: thread t handles f32x4 idx {t, 512+t}
  const int arow0 = t >> 4;             // row for chunk 0 (chunk 1: +32)
  const int ak0   = (t & 15) * 4;

  const int w0 = blockIdx.x * 16;

  // ---- x DMA staging: 8 instrs; wave wvi loads tok = j*8+wvi, lane l holds
  // ch-granule (l ^ (tok&31)); LDS dest linear -> swizzled tile emerges. ----
#define STAGE_X(W, BUFOFF) do {                                            \
    const float* xp_ = x + wbase(W);                                       \
    _Pragma("unroll")                                                      \
    for (int j = 0; j < 8; ++j) {                                          \
      int tok_ = j * 8 + wvi;                                              \
      int ch0_ = (lane ^ (tok_ & 31)) * 4;                                 \
      const float* gp_ = xp_ + (tok_ >> 3) * 65536 + (tok_ & 7) * 256 + ch0_; \
      int off_ = __builtin_amdgcn_readfirstlane((BUFOFF) + j * 8192 + wvi * 1024); \
      dma16(gp_, lds + off_);                                              \
    } } while (0)

  // ---- prologue: stage window w0 into buffer 0 ----
  STAGE_X(w0, 0);
  {
    const float* ap = attn + (long)w0 * 4096;
    f32x4 a0 = *(const f32x4*)(ap + t * 4);
    f32x4 a1 = *(const f32x4*)(ap + (512 + t) * 4);
    char* bat = lds + 131072;
    *(bf16x4*)(bat + arow0 * 128 + ((ak0 * 2) ^ ((arow0 & 7) << 4))) =
        bf16x4{ (__bf16)a0.x, (__bf16)a0.y, (__bf16)a0.z, (__bf16)a0.w };
    int row1 = 32 + arow0;
    *(bf16x4*)(bat + row1 * 128 + ((ak0 * 2) ^ ((row1 & 7) << 4))) =
        bf16x4{ (__bf16)a1.x, (__bf16)a1.y, (__bf16)a1.z, (__bf16)a1.w };
  }
  asm volatile("s_waitcnt vmcnt(0) lgkmcnt(0)" ::: "memory");
  __builtin_amdgcn_s_barrier();
  __builtin_amdgcn_sched_barrier(0);

#pragma unroll 1
  for (int i = 0; i < 16; ++i) {
    const int w = w0 + i;
    const char* xs = lds + (i & 1) * 65536;
    const char* as = lds + 131072 + (i & 1) * 8192;

    // ---- issue next window's attn loads (8 VGPRs) + x DMAs ----
    f32x4 ra0, ra1;
    if (i < 15) {
      const float* ap = attn + (long)(w + 1) * 4096;
      ra0 = *(const f32x4*)(ap + t * 4);
      ra1 = *(const f32x4*)(ap + (512 + t) * 4);
      STAGE_X(w + 1, ((i + 1) & 1) * 65536);
    }
    __builtin_amdgcn_sched_barrier(0);   // pin: all issues before GEMM1

    // ---- GEMM1: z[tok][ch] = xw @ W, K=256 (A from f32 LDS + cvt) ----
    f32x16 acc0 = {}, acc1 = {};
#pragma unroll 4
    for (int ks = 0; ks < 16; ++ks) {
      int g = 4 * ks + 2 * lh;
      bf16x8 a0 = ldax(xs, ln31, g);            // toks 0..31
      bf16x8 a1 = ldax(xs, 32 + ln31, g);       // toks 32..63
      bf16x8 b0 = *(const bf16x8*)(wtp + ks * 16);
      acc0 = MFMA32(a0, b0, acc0);
      acc1 = MFMA32(a1, b0, acc1);
    }

    // ---- GEMM2 B-frags in-register ----
    bf16x8 bfr[4];
    build_bfrags(acc0, lh, &bfr[0]);
    build_bfrags(acc1, lh, &bfr[2]);

    // ---- GEMM2: out[tok][ch] = attn @ z, K=64 (attn bf16 LDS) ----
    f32x16 o0 = {}, o1 = {};
#pragma unroll
    for (int ks = 0; ks < 4; ++ks) {
      int kk = ks * 16 + 8 * lh;
      int ab0 = ln31 * 128 + ((kk * 2) ^ ((ln31 & 7) << 4));
      bf16x8 a0 = *(const bf16x8*)(as + ab0);
      bf16x8 a1 = *(const bf16x8*)(as + ab0 + 4096);
      o0 = MFMA32(a0, bfr[ks], o0);
      o1 = MFMA32(a1, bfr[ks], o1);
    }

    // ---- epilogue: + bo, scatter-store window w (32 dword stores) ----
    {
      float* op = out + wbase(w);
      const int ch = wvi * 32 + ln31;
#pragma unroll
      for (int r = 0; r < 16; ++r) {
        int tok = (r & 3) + 8 * (r >> 2) + 4 * lh;
        op[(tok >> 3) * 65536 + (tok & 7) * 256 + ch] = o0[r] + bv;
      }
#pragma unroll
      for (int r = 0; r < 16; ++r) {
        int tok = 32 + (r & 3) + 8 * (r >> 2) + 4 * lh;
        op[(tok >> 3) * 65536 + (tok & 7) * 256 + ch] = o1[r] + bv;
      }
    }

    // ---- attn cvt + ds_write for w+1 ----
    if (i < 15) {
      char* bat = lds + 131072 + ((i + 1) & 1) * 8192;
      *(bf16x4*)(bat + arow0 * 128 + ((ak0 * 2) ^ ((arow0 & 7) << 4))) =
          bf16x4{ (__bf16)ra0.x, (__bf16)ra0.y, (__bf16)ra0.z, (__bf16)ra0.w };
      int row1 = 32 + arow0;
      *(bf16x4*)(bat + row1 * 128 + ((ak0 * 2) ^ ((row1 & 7) << 4))) =
          bf16x4{ (__bf16)ra1.x, (__bf16)ra1.y, (__bf16)ra1.z, (__bf16)ra1.w };
    }

    // ---- counted drain (THE R9 change): allow the 32 newest VMEM ops
    // (this window's stores) to stay in flight; everything older (next
    // window's 8 DMAs + attn loads) must be done before the barrier. ----
    asm volatile("s_waitcnt vmcnt(32) lgkmcnt(0)" ::: "memory");
    __builtin_amdgcn_s_barrier();
    __builtin_amdgcn_sched_barrier(0);
  }
#undef STAGE_X
}

extern "C" void kernel_launch(void* const* d_in, const int* in_sizes, int n_in,
                              void* d_out, int out_size, void* d_ws, size_t ws_size,
                              hipStream_t stream) {
  const float* x    = (const float*)d_in[0];
  const float* attn = (const float*)d_in[1];
  const float* Wv   = (const float*)d_in[2];
  const float* Wo   = (const float*)d_in[3];
  const float* bo   = (const float*)d_in[4];
  float* out = (float*)d_out;
  __bf16* WT = (__bf16*)d_ws;   // 256*256*2 = 128 KB scratch

  wfuse_kernel<<<256, 256, 0, stream>>>(Wv, Wo, WT);
  na_msa_kernel<<<256, 512, 0, stream>>>(x, attn, WT, bo, out);
}